// Round 1
// baseline (10384.847 us; speedup 1.0000x reference)
//
#include <hip/hip_runtime.h>
#include <cstdint>

#define HID  256
#define NG   1024   // 4*HID
#define TT   256
#define WIN  128
#define K0   264    // 8 input feats + 256 h0
#define K1   512    // 256 h0 + 256 h1
#define OUTW 129

__device__ __forceinline__ float sigm(float z)  { return 1.0f / (1.0f + __expf(-z)); }
__device__ __forceinline__ float tanhx(float z) { float e = __expf(2.0f * z); return 1.0f - 2.0f / (e + 1.0f); }

// ---------------------------------------------------------------------------
// prep: build k-major (transposed) weight panels + fused biases in d_ws.
//   WT0[k][g], k<8 -> W_ih0[g][k], else W_hh0[g][k-8]          (K0 x NG)
//   WT1[k][g], k<256 -> W_ih1[g][k], else W_hh1[g][k-256]      (K1 x NG)
//   bs0[g] = b_ih0[g]+b_hh0[g] ; bs1 likewise
// ---------------------------------------------------------------------------
__global__ void prep_kernel(const float* __restrict__ Wih0, const float* __restrict__ Whh0,
                            const float* __restrict__ bih0, const float* __restrict__ bhh0,
                            const float* __restrict__ Wih1, const float* __restrict__ Whh1,
                            const float* __restrict__ bih1, const float* __restrict__ bhh1,
                            float* __restrict__ ws) {
  const int n0 = K0 * NG, n1 = K1 * NG;
  const int total = n0 + n1 + 2 * NG;
  for (int i = blockIdx.x * blockDim.x + threadIdx.x; i < total; i += gridDim.x * blockDim.x) {
    float v;
    if (i < n0) {
      int k = i >> 10, g = i & (NG - 1);
      v = (k < 8) ? Wih0[g * 8 + k] : Whh0[g * HID + (k - 8)];
    } else if (i < n0 + n1) {
      int j = i - n0;
      int k = j >> 10, g = j & (NG - 1);
      v = (k < HID) ? Wih1[g * HID + k] : Whh1[g * HID + (k - HID)];
    } else if (i < n0 + n1 + NG) {
      int g = i - n0 - n1;
      v = bih0[g] + bhh0[g];
    } else {
      int g = i - n0 - n1 - NG;
      v = bih1[g] + bhh1[g];
    }
    ws[i] = v;
  }
}

// ---------------------------------------------------------------------------
// Persistent kernel: 256 blocks (1/CU) x 256 threads; block owns 4 batch rows.
// Entire 256-step recurrence in one launch; batch rows are independent so
// only block-level syncs are needed.
// ---------------------------------------------------------------------------
__global__ __launch_bounds__(256) void lstm_ar_kernel(
    const float* __restrict__ x, const float* __restrict__ Wlin,
    const float* __restrict__ blin, const float* __restrict__ ws,
    float* __restrict__ out)
{
  const float* __restrict__ WT0 = ws;
  const float* __restrict__ WT1 = ws + K0 * NG;
  const float* __restrict__ bs0 = ws + (K0 + K1) * NG;
  const float* __restrict__ bs1 = bs0 + NG;

  __shared__ float in0[K0][4];     // layer0 input, k-major: k<8 = [pred|x feats], k>=8 = h0_prev
  __shared__ float in1[K1][4];     // k<256 = h0_new, k>=256 = h1_prev
  __shared__ float c0s[HID][4];
  __shared__ float c1s[HID][4];
  __shared__ float gl[4][NG];      // gate scratch, [row][gate]
  __shared__ float predl[4];

  const int tid = threadIdx.x;
  const int r0  = blockIdx.x << 2;  // first batch row of this block

  // zero-init state (tid == hidden index j, HID==blockDim)
  {
    float4 z = make_float4(0.f, 0.f, 0.f, 0.f);
    *(float4*)&c0s[tid][0]       = z;
    *(float4*)&c1s[tid][0]       = z;
    *(float4*)&in0[8 + tid][0]   = z;
    *(float4*)&in1[tid][0]       = z;
    *(float4*)&in1[HID + tid][0] = z;
  }
  __syncthreads();

  for (int t = 0; t < TT; ++t) {
    // ---- input staging: 8 features x 4 rows ----
    if (tid < 32) {
      int r = tid >> 3, k = tid & 7;
      float v;
      if (t >= WIN && k == 0) v = predl[r];                       // AR feedback
      else v = x[((size_t)(r0 + r) * TT + t) * 8 + k];
      in0[k][r] = v;
    }
    __syncthreads();

    // ---- layer 0 gates: thread owns gates 4t..4t+3 for all 4 rows ----
    {
      const int g4 = tid << 2;
      float4 b = *(const float4*)&bs0[g4];
      float4 a0 = b, a1 = b, a2 = b, a3 = b;
      #pragma unroll 4
      for (int k = 0; k < K0; ++k) {
        const float4 w = *(const float4*)&WT0[(k << 10) + g4];    // coalesced
        const float4 h = *(const float4*)&in0[k][0];              // LDS broadcast
        a0.x += w.x * h.x; a0.y += w.y * h.x; a0.z += w.z * h.x; a0.w += w.w * h.x;
        a1.x += w.x * h.y; a1.y += w.y * h.y; a1.z += w.z * h.y; a1.w += w.w * h.y;
        a2.x += w.x * h.z; a2.y += w.y * h.z; a2.z += w.z * h.z; a2.w += w.w * h.z;
        a3.x += w.x * h.w; a3.y += w.y * h.w; a3.z += w.z * h.w; a3.w += w.w * h.w;
      }
      *(float4*)&gl[0][g4] = a0;
      *(float4*)&gl[1][g4] = a1;
      *(float4*)&gl[2][g4] = a2;
      *(float4*)&gl[3][g4] = a3;
    }
    __syncthreads();

    // ---- epilogue 0: thread == hidden index j ----
    {
      const int j = tid;
      float4 c = *(const float4*)&c0s[j][0];
      float cc[4] = {c.x, c.y, c.z, c.w};
      float hh[4];
      #pragma unroll
      for (int r = 0; r < 4; ++r) {
        float ig = sigm(gl[r][j]);
        float fg = sigm(gl[r][HID + j]);
        float gg = tanhx(gl[r][2 * HID + j]);
        float og = sigm(gl[r][3 * HID + j]);
        float cn = fg * cc[r] + ig * gg;
        cc[r] = cn;
        hh[r] = og * tanhx(cn);
      }
      *(float4*)&c0s[j][0] = make_float4(cc[0], cc[1], cc[2], cc[3]);
      float4 hv = make_float4(hh[0], hh[1], hh[2], hh[3]);
      *(float4*)&in0[8 + j][0] = hv;    // h0 for next step's layer0
      *(float4*)&in1[j][0]     = hv;    // h0 for this step's layer1
    }
    __syncthreads();

    // ---- layer 1 gates ----
    {
      const int g4 = tid << 2;
      float4 b = *(const float4*)&bs1[g4];
      float4 a0 = b, a1 = b, a2 = b, a3 = b;
      #pragma unroll 4
      for (int k = 0; k < K1; ++k) {
        const float4 w = *(const float4*)&WT1[(k << 10) + g4];
        const float4 h = *(const float4*)&in1[k][0];
        a0.x += w.x * h.x; a0.y += w.y * h.x; a0.z += w.z * h.x; a0.w += w.w * h.x;
        a1.x += w.x * h.y; a1.y += w.y * h.y; a1.z += w.z * h.y; a1.w += w.w * h.y;
        a2.x += w.x * h.z; a2.y += w.y * h.z; a2.z += w.z * h.z; a2.w += w.w * h.z;
        a3.x += w.x * h.w; a3.y += w.y * h.w; a3.z += w.z * h.w; a3.w += w.w * h.w;
      }
      *(float4*)&gl[0][g4] = a0;
      *(float4*)&gl[1][g4] = a1;
      *(float4*)&gl[2][g4] = a2;
      *(float4*)&gl[3][g4] = a3;
    }
    __syncthreads();

    // ---- epilogue 1 ----
    {
      const int j = tid;
      float4 c = *(const float4*)&c1s[j][0];
      float cc[4] = {c.x, c.y, c.z, c.w};
      float hh[4];
      #pragma unroll
      for (int r = 0; r < 4; ++r) {
        float ig = sigm(gl[r][j]);
        float fg = sigm(gl[r][HID + j]);
        float gg = tanhx(gl[r][2 * HID + j]);
        float og = sigm(gl[r][3 * HID + j]);
        float cn = fg * cc[r] + ig * gg;
        cc[r] = cn;
        hh[r] = og * tanhx(cn);
      }
      *(float4*)&c1s[j][0] = make_float4(cc[0], cc[1], cc[2], cc[3]);
      *(float4*)&in1[HID + j][0] = make_float4(hh[0], hh[1], hh[2], hh[3]); // h1
    }
    __syncthreads();

    // ---- prediction: wave w handles batch row w ----
    if (t >= WIN - 1) {
      const int w = tid >> 6, l = tid & 63;
      float s = 0.f;
      #pragma unroll
      for (int q = 0; q < 4; ++q) {
        int j = l + (q << 6);
        s += Wlin[j] * in1[HID + j][w];
      }
      #pragma unroll
      for (int off = 32; off; off >>= 1) s += __shfl_down(s, off);
      if (l == 0) {
        float p = s + blin[0];
        predl[w] = p;
        out[(size_t)(r0 + w) * OUTW + (t - (WIN - 1))] = p;
      }
    }
    __syncthreads();
  }
}

// ---------------------------------------------------------------------------
extern "C" void kernel_launch(void* const* d_in, const int* in_sizes, int n_in,
                              void* d_out, int out_size, void* d_ws, size_t ws_size,
                              hipStream_t stream) {
  (void)in_sizes; (void)n_in; (void)out_size; (void)ws_size;
  const float* x    = (const float*)d_in[0];
  const float* Wih0 = (const float*)d_in[1];
  const float* Whh0 = (const float*)d_in[2];
  const float* bih0 = (const float*)d_in[3];
  const float* bhh0 = (const float*)d_in[4];
  const float* Wih1 = (const float*)d_in[5];
  const float* Whh1 = (const float*)d_in[6];
  const float* bih1 = (const float*)d_in[7];
  const float* bhh1 = (const float*)d_in[8];
  const float* Wlin = (const float*)d_in[9];
  const float* blin = (const float*)d_in[10];
  float* ws  = (float*)d_ws;
  float* out = (float*)d_out;

  prep_kernel<<<256, 256, 0, stream>>>(Wih0, Whh0, bih0, bhh0,
                                       Wih1, Whh1, bih1, bhh1, ws);
  lstm_ar_kernel<<<256, 256, 0, stream>>>(x, Wlin, blin, ws, out);
}